// Round 7
// baseline (227.126 us; speedup 1.0000x reference)
//
#include <hip/hip_runtime.h>

// Problem constants
#define N_TOK 16384
#define CIN   512
#define COUT  512
#define NE    8
// 128x128 tile, BK=64, 4 waves (2M x 2N) -> 64x64/wave; A in regs, B in LDS; 2 blocks/CU
#define BM    128
#define BN    128
#define BK    64
#define KTILES 64        // 8 experts x 8 k-chunks

typedef __attribute__((ext_vector_type(8))) short bf16x8;
typedef __attribute__((ext_vector_type(4))) short s16x4;
typedef __attribute__((ext_vector_type(4))) float f32x4;

__device__ __forceinline__ short f2bf(float f) {
  unsigned u = __builtin_bit_cast(unsigned, f);
  u += 0x7FFFu + ((u >> 16) & 1u);   // RNE
  return (short)(u >> 16);
}

// fused f32->bf16 for x and w, grid-stride
__global__ void cvt_all(const float4* __restrict__ x, const float4* __restrict__ w,
                        s16x4* __restrict__ xb, s16x4* __restrict__ wb) {
  const int NX = N_TOK * CIN / 4;
  const int NT = NX + NE * COUT * CIN / 4;
  for (int i = blockIdx.x * blockDim.x + threadIdx.x; i < NT; i += gridDim.x * blockDim.x) {
    float4 v; s16x4* o;
    if (i < NX) { v = x[i]; o = xb + i; }
    else        { int j = i - NX; v = w[j]; o = wb + j; }
    s16x4 r;
    r[0] = f2bf(v.x); r[1] = f2bf(v.y); r[2] = f2bf(v.z); r[3] = f2bf(v.w);
    *o = r;
  }
}

__device__ __forceinline__ void async16(short* lds, const short* g) {
  __builtin_amdgcn_global_load_lds(
      (const __attribute__((address_space(1))) void*)g,
      (__attribute__((address_space(3))) void*)lds, 16, 0, 0);
}

// out[n,o] = sum_e coef[n,e] * sum_i x[n,i]*W[e,o,i] + sum_e coef[n,e]*bias[e,o]
// Single accumulator via Horner rescaling: acc holds (sum_{e'<=e} c_e' S_e') / c_e.
__global__ __launch_bounds__(256, 2)
void moe_gemm(const short* __restrict__ xb,    // [N_TOK][CIN] bf16
              const short* __restrict__ wb,    // [NE][COUT][CIN] bf16
              const float* __restrict__ coef,  // [N_TOK][NE] f32
              const float* __restrict__ bias,  // [NE][COUT] f32
              float* __restrict__ out) {       // [N_TOK][COUT] f32
  __shared__ short Bs[2][BN * BK];   // 2 x 16KB
  __shared__ float cfc[BM * NE];     // 4KB raw coef
  __shared__ float cfr[BM * NE];     // 4KB Horner ratios   (40KB total -> 2 blocks/CU)

  const int tid  = threadIdx.x;
  const int lane = tid & 63;
  const int wid  = tid >> 6;   // 0..3
  const int wm   = wid >> 1;   // 0..1  (64-row slab)
  const int wn   = wid & 1;    // 0..1  (64-col slab)
  const int lhi  = lane >> 4;  // 0..3
  const int llo  = lane & 15;

  // XCD ct-partition swizzle: 512 blocks = 8 XCDs x 64; XCD x -> fixed ct = x&3
  // => per-XCD B working set = 1MB (L2-resident), x rows streamed once per XCD.
  const int bid0 = blockIdx.x;
  const int xx   = bid0 & 7;
  const int jj   = bid0 >> 3;              // 0..63
  const int rt   = (xx >> 2) * 64 + jj;    // 0..127
  const int ct   = xx & 3;
  const int row0 = rt * BM;
  const int col0 = ct * BN;

  // coef tile: 128 rows x 8 f32 = 4KB = 256 thr x float4
  ((float4*)cfc)[tid] = ((const float4*)(coef + row0 * NE))[tid];

  // ---- B staging: pass = 256 thr x 16B = 4KB = 32 rows; 4 passes per 16KB tile.
  // T2 both-sides XOR swizzle: LDS dest linear (gload_lds), SOURCE col pre-swizzled.
  const int r_st = tid >> 3;                               // 0..31
  const int c_sw = ((tid & 7) * 8) ^ ((r_st & 7) << 3);    // swizzled col (shorts)
  const short* gB = wb + (size_t)(col0 + r_st) * CIN + c_sw;

  auto stageB = [&](int buf, int t) {
    const int e  = t >> 3;
    const int i0 = (t & 7) * BK;
#pragma unroll
    for (int p = 0; p < 4; ++p)
      async16(&Bs[buf][p * 2048 + tid * 8],
              gB + (size_t)e * (CIN * COUT) + p * 32 * CIN + i0);
  };

  // ---- A direct global->reg in MFMA fragment layout (no LDS, no swizzle):
  // frag(m,ks): row = row0 + wm*64 + m*16 + llo, k = (t&7)*64 + ks*32 + lhi*8 .. +7
  // NOTE: x's K axis is CIN=512 and is REUSED by every expert -> (t&7), NOT t.
  // (round-5/6 bug: t*64 walked past the row into subsequent x rows for t>=8)
  const short* gA = xb + (size_t)(row0 + wm * 64 + llo) * CIN + lhi * 8;
  auto loadA = [&](bf16x8 dst[4][2], int t) {
    const int i0 = (t & 7) * 64;
#pragma unroll
    for (int m = 0; m < 4; ++m)
#pragma unroll
      for (int ks = 0; ks < 2; ++ks)
        dst[m][ks] = *(const bf16x8*)(gA + (size_t)m * 16 * CIN + i0 + ks * 32);
  };

  // B fragment read offsets (element [row][col] lives at [row][col ^ ((row&7)<<3)])
  const int swz0 = (lhi * 8) ^ ((llo & 7) << 3);
  const int swz1 = (32 + lhi * 8) ^ ((llo & 7) << 3);
  const int brow = wn * 64 + llo;

  f32x4 acc[4][4];
#pragma unroll
  for (int m = 0; m < 4; ++m)
#pragma unroll
    for (int n = 0; n < 4; ++n)
      acc[m][n] = (f32x4){0.f, 0.f, 0.f, 0.f};

  bf16x8 af0[4][2], af1[4][2];

  // ---- prologue: tile 0 into buf0/af0; cfc -> cfr
  stageB(0, 0);
  loadA(af0, 0);
  __syncthreads();                       // cfc visible (also drains vmcnt: tile0 staged)
  if (tid < BM) {
    const float* cp = &cfc[tid * NE];
    float c[NE];
#pragma unroll
    for (int e = 0; e < NE; ++e) c[e] = fmaxf(cp[e], 1e-20f);
    float* rp = &cfr[tid * NE];
#pragma unroll
    for (int e = 0; e < NE - 1; ++e) rp[e] = c[e] / c[e + 1];
    rp[NE - 1] = c[NE - 1];
  }
  __syncthreads();                       // cfr visible

  auto tilebody = [&](bf16x8 (&cur)[4][2], bf16x8 (&nxt)[4][2], int t) {
    const int buf = t & 1;
    if (t + 1 < KTILES) {
      loadA(nxt, t + 1);                 // 8 global dwordx4 -> regs (compiler-tracked)
      stageB(buf ^ 1, t + 1);            // 4 global_load_lds
    }
    const short* Bb = Bs[buf];
    bf16x8 bf[4][2];
#pragma unroll
    for (int n = 0; n < 4; ++n) {
      bf[n][0] = *(const bf16x8*)&Bb[(brow + n * 16) * 64 + swz0];
      bf[n][1] = *(const bf16x8*)&Bb[(brow + n * 16) * 64 + swz1];
    }
    __builtin_amdgcn_s_setprio(1);
#pragma unroll
    for (int m = 0; m < 4; ++m)
#pragma unroll
      for (int n = 0; n < 4; ++n)
#pragma unroll
        for (int ks = 0; ks < 2; ++ks)
          acc[m][n] = __builtin_amdgcn_mfma_f32_16x16x32_bf16(
              cur[m][ks], bf[n][ks], acc[m][n], 0, 0, 0);
    __builtin_amdgcn_s_setprio(0);

    // expert boundary: Horner rescale acc *= c'_e/c'_{e+1} (e=7: *= c'_7)
    if ((t & 7) == 7) {
      const int e = t >> 3;
#pragma unroll
      for (int m = 0; m < 4; ++m)
#pragma unroll
        for (int r = 0; r < 4; ++r) {
          float rr = cfr[(wm * 64 + m * 16 + lhi * 4 + r) * NE + e];
#pragma unroll
          for (int n = 0; n < 4; ++n)
            acc[m][n][r] *= rr;
        }
    }

    // tile boundary: FULL fence (vmcnt+lgkmcnt drain + barrier + compiler fence).
    if (t + 1 < KTILES) __syncthreads();
  };

  for (int t = 0; t < KTILES; t += 2) {
    tilebody(af0, af1, t);
    tilebody(af1, af0, t + 1);
  }

  // ---- epilogue: out = acc + sum_e coef[n,e]*bias[e,o]
  float bcol[4][NE];
#pragma unroll
  for (int n = 0; n < 4; ++n) {
    const int cg = col0 + wn * 64 + n * 16 + llo;
#pragma unroll
    for (int e = 0; e < NE; ++e) bcol[n][e] = bias[e * COUT + cg];
  }
#pragma unroll
  for (int m = 0; m < 4; ++m)
#pragma unroll
    for (int r = 0; r < 4; ++r) {
      const int rl = wm * 64 + m * 16 + lhi * 4 + r;
      float cv[NE];
#pragma unroll
      for (int e = 0; e < NE; ++e) cv[e] = cfc[rl * NE + e];
      float* orow = out + (size_t)(row0 + rl) * COUT;
#pragma unroll
      for (int n = 0; n < 4; ++n) {
        float bm = 0.f;
#pragma unroll
        for (int e = 0; e < NE; ++e) bm += cv[e] * bcol[n][e];
        orow[col0 + wn * 64 + n * 16 + llo] = acc[m][n][r] + bm;
      }
    }
}

extern "C" void kernel_launch(void* const* d_in, const int* in_sizes, int n_in,
                              void* d_out, int out_size, void* d_ws, size_t ws_size,
                              hipStream_t stream) {
  const float* x    = (const float*)d_in[0];  // [16384][512]
  const float* coef = (const float*)d_in[1];  // [16384][8]
  const float* w    = (const float*)d_in[2];  // [8][512][512]
  const float* bias = (const float*)d_in[3];  // [8][512]
  float* out = (float*)d_out;

  short* xb = (short*)d_ws;                   // 16 MB bf16 x
  short* wb = xb + (size_t)N_TOK * CIN;       // 4 MB bf16 weight

  cvt_all<<<2048, 256, 0, stream>>>(
      (const float4*)x, (const float4*)w, (s16x4*)xb, (s16x4*)wb);

  moe_gemm<<<(N_TOK / BM) * (COUT / BN), 256, 0, stream>>>(xb, wb, coef, bias, out);
}

// Round 9
// 183.623 us; speedup vs baseline: 1.2369x; 1.2369x over previous
//
#include <hip/hip_runtime.h>

// Problem constants
#define N_TOK 16384
#define CIN   512
#define COUT  512
#define NE    8
// 256x128 tile, BK=64, 8 waves (4M x 2N) -> 64x64/wave; triple-buffer LDS, counted vmcnt
#define BM    256
#define BN    128
#define BK    64
#define KTILES 64        // 8 experts x 8 k-chunks

typedef __attribute__((ext_vector_type(8))) short bf16x8;
typedef __attribute__((ext_vector_type(4))) short s16x4;
typedef __attribute__((ext_vector_type(4))) float f32x4;

__device__ __forceinline__ short f2bf(float f) {
  unsigned u = __builtin_bit_cast(unsigned, f);
  u += 0x7FFFu + ((u >> 16) & 1u);   // RNE
  return (short)(u >> 16);
}

// fused f32->bf16 for x and w, grid-stride
__global__ void cvt_all(const float4* __restrict__ x, const float4* __restrict__ w,
                        s16x4* __restrict__ xb, s16x4* __restrict__ wb) {
  const int NX = N_TOK * CIN / 4;
  const int NT = NX + NE * COUT * CIN / 4;
  for (int i = blockIdx.x * blockDim.x + threadIdx.x; i < NT; i += gridDim.x * blockDim.x) {
    float4 v; s16x4* o;
    if (i < NX) { v = x[i]; o = xb + i; }
    else        { int j = i - NX; v = w[j]; o = wb + j; }
    s16x4 r;
    r[0] = f2bf(v.x); r[1] = f2bf(v.y); r[2] = f2bf(v.z); r[3] = f2bf(v.w);
    *o = r;
  }
}

__device__ __forceinline__ void async16(short* lds, const short* g) {
  __builtin_amdgcn_global_load_lds(
      (const __attribute__((address_space(1))) void*)g,
      (__attribute__((address_space(3))) void*)lds, 16, 0, 0);
}

#define SBAR()  do { __builtin_amdgcn_sched_barrier(0); __builtin_amdgcn_s_barrier(); \
                     __builtin_amdgcn_sched_barrier(0); } while (0)
#define WAIT_LGKM0() do { asm volatile("s_waitcnt lgkmcnt(0)" ::: "memory"); \
                          __builtin_amdgcn_sched_barrier(0); } while (0)

// out[n,o] = sum_e coef[n,e] * (sum_i x[n,i]*W[e,o,i] + bias[e,o])
// Single accumulator, Horner rescaling WITH bias folded at each expert boundary:
//   boundary e: acc = (acc + bias_e) * r_e,  r_e = c'_e/c'_{e+1} (e<7), r_7 = c'_7.
__global__ __launch_bounds__(512, 2)
void moe_gemm(const short* __restrict__ xb,    // [N_TOK][CIN] bf16
              const short* __restrict__ wb,    // [NE][COUT][CIN] bf16
              const float* __restrict__ coef,  // [N_TOK][NE] f32
              const float* __restrict__ bias,  // [NE][COUT] f32
              float* __restrict__ out) {       // [N_TOK][COUT] f32
  __shared__ short As[3][BM * BK];   // 3 x 32KB
  __shared__ short Bs[3][BN * BK];   // 3 x 16KB
  __shared__ float cfr[BM * NE];     // 8KB Horner ratios
  __shared__ float bb[NE * BN];      // 4KB block's bias cols   (total 156KB, 1 blk/CU)

  const int tid  = threadIdx.x;
  const int lane = tid & 63;
  const int wid  = tid >> 6;   // 0..7
  const int wm   = wid >> 1;   // 0..3  (64-row slab)
  const int wn   = wid & 1;    // 0..1  (64-col slab)
  const int lhi  = lane >> 4;  // 0..3
  const int llo  = lane & 15;

  // XCD ct-partition: 256 blocks = 8 XCDs x 32; XCD x -> fixed ct = x&3
  // => per-XCD W working set = 1MB (L2-resident).
  const int bid0 = blockIdx.x;
  const int xx   = bid0 & 7;
  const int jj   = bid0 >> 3;              // 0..31
  const int rt   = (xx >> 2) * 32 + jj;    // 0..63
  const int ct   = xx & 3;
  const int row0 = rt * BM;
  const int col0 = ct * BN;

  // ---- staging: pass = 512 thr x 16B = 8KB = 64 rows of 64k; A 4 passes, B 2.
  // T2 both-sides XOR swizzle: LDS dest linear (gload_lds), SOURCE col pre-swizzled.
  const int r_st = tid >> 3;                               // 0..63
  const int c_sw = ((tid & 7) * 8) ^ ((r_st & 7) << 3);    // swizzled col (shorts)
  const short* gA = xb + (size_t)(row0 + r_st) * CIN + c_sw;
  const short* gB = wb + (size_t)(col0 + r_st) * CIN + c_sw;

  auto stageA = [&](int buf, int t) {      // 4 gloads; x reuses K per expert -> (t&7)
    const int i0 = (t & 7) * BK;
#pragma unroll
    for (int p = 0; p < 4; ++p)
      async16(&As[buf][p * 4096 + tid * 8], gA + p * 64 * CIN + i0);
  };
  auto stageB = [&](int buf, int t) {      // 2 gloads
    const int e  = t >> 3;
    const int i0 = (t & 7) * BK;
#pragma unroll
    for (int p = 0; p < 2; ++p)
      async16(&Bs[buf][p * 4096 + tid * 8],
              gB + (size_t)e * (CIN * COUT) + p * 64 * CIN + i0);
  };

  // ---- prologue: bias tile, Horner ratios, stage tiles 0 and 1
  if (tid < 256) {                         // bb[e][c], 8 x 128 f32 via float4
    const int e = tid >> 5, c4 = tid & 31;
    ((float4*)bb)[tid] = ((const float4*)(bias + e * COUT + col0))[c4];
  }
  if (tid < BM) {                          // ratio table, one thread per row
    const float4* cp = (const float4*)(coef + (size_t)(row0 + tid) * NE);
    float4 cl = cp[0], ch = cp[1];
    float c[NE] = {cl.x, cl.y, cl.z, cl.w, ch.x, ch.y, ch.z, ch.w};
#pragma unroll
    for (int e = 0; e < NE; ++e) c[e] = fmaxf(c[e], 1e-20f);
    float* rp = &cfr[tid * NE];
#pragma unroll
    for (int e = 0; e < NE - 1; ++e) rp[e] = c[e] / c[e + 1];
    rp[NE - 1] = c[NE - 1];
  }
  stageA(0, 0); stageB(0, 0);
  stageA(1, 1); stageB(1, 1);
  __syncthreads();                         // bb/cfr visible; tiles 0,1 landed (full drain, once)

  // fragment read offsets: element [row][col] lives at [row][col ^ ((row&7)<<3)]
  const int swz0 = (lhi * 8) ^ ((llo & 7) << 3);
  const int swz1 = (32 + lhi * 8) ^ ((llo & 7) << 3);
  const int arow = wm * 64 + llo;
  const int brow = wn * 64 + llo;

  f32x4 acc[4][4];
#pragma unroll
  for (int m = 0; m < 4; ++m)
#pragma unroll
    for (int n = 0; n < 4; ++n)
      acc[m][n] = (f32x4){0.f, 0.f, 0.f, 0.f};

  int cur = 0;                             // t%3
  for (int t = 0; t < KTILES; ++t) {
    const int nx2 = (cur < 1) ? cur + 2 : cur - 1;   // (t+2)%3
    const short* Ab = As[cur];
    const short* Bb = Bs[cur];
    const bool pf = (t + 2) < KTILES;

    // ===== phase 0: stage A(t+2) | read af(m0,m1)+all bf | 16 MFMA =====
    if (pf) stageA(nx2, t + 2);
    bf16x8 af[2][2], bf[4][2];
#pragma unroll
    for (int n = 0; n < 4; ++n) {
      bf[n][0] = *(const bf16x8*)&Bb[(brow + n * 16) * 64 + swz0];
      bf[n][1] = *(const bf16x8*)&Bb[(brow + n * 16) * 64 + swz1];
    }
#pragma unroll
    for (int mm = 0; mm < 2; ++mm) {
      af[mm][0] = *(const bf16x8*)&Ab[(arow + mm * 16) * 64 + swz0];
      af[mm][1] = *(const bf16x8*)&Ab[(arow + mm * 16) * 64 + swz1];
    }
    SBAR();
    WAIT_LGKM0();
    __builtin_amdgcn_s_setprio(1);
#pragma unroll
    for (int mm = 0; mm < 2; ++mm)
#pragma unroll
      for (int n = 0; n < 4; ++n)
#pragma unroll
        for (int ks = 0; ks < 2; ++ks)
          acc[mm][n] = __builtin_amdgcn_mfma_f32_16x16x32_bf16(
              af[mm][ks], bf[n][ks], acc[mm][n], 0, 0, 0);
    __builtin_amdgcn_s_setprio(0);
    SBAR();

    // ===== phase 1: stage B(t+2) | read af(m2,m3) | 16 MFMA =====
    if (pf) stageB(nx2, t + 2);
#pragma unroll
    for (int mm = 0; mm < 2; ++mm) {
      af[mm][0] = *(const bf16x8*)&Ab[(arow + (2 + mm) * 16) * 64 + swz0];
      af[mm][1] = *(const bf16x8*)&Ab[(arow + (2 + mm) * 16) * 64 + swz1];
    }
    SBAR();
    WAIT_LGKM0();
    __builtin_amdgcn_s_setprio(1);
#pragma unroll
    for (int mm = 0; mm < 2; ++mm)
#pragma unroll
      for (int n = 0; n < 4; ++n)
#pragma unroll
        for (int ks = 0; ks < 2; ++ks)
          acc[2 + mm][n] = __builtin_amdgcn_mfma_f32_16x16x32_bf16(
              af[mm][ks], bf[n][ks], acc[2 + mm][n], 0, 0, 0);
    __builtin_amdgcn_s_setprio(0);

    // ===== expert boundary: acc = (acc + bias_e) * ratio_e =====
    if ((t & 7) == 7) {
      const int e = t >> 3;
      float bv[4];
#pragma unroll
      for (int n = 0; n < 4; ++n) bv[n] = bb[e * BN + wn * 64 + n * 16 + llo];
#pragma unroll
      for (int m = 0; m < 4; ++m)
#pragma unroll
        for (int r = 0; r < 4; ++r) {
          float rr = cfr[(wm * 64 + m * 16 + lhi * 4 + r) * NE + e];
#pragma unroll
          for (int n = 0; n < 4; ++n)
            acc[m][n][r] = (acc[m][n][r] + bv[n]) * rr;
        }
    }

    // ===== tile boundary: counted vmcnt — t+1's 6 landed, t+2's 6 stay in flight =====
    if (pf) {
      asm volatile("s_waitcnt vmcnt(6)" ::: "memory");
      __builtin_amdgcn_sched_barrier(0);
      SBAR();
    } else if (t + 1 < KTILES) {           // t == KTILES-2: only t+1's 6 outstanding
      asm volatile("s_waitcnt vmcnt(0)" ::: "memory");
      __builtin_amdgcn_sched_barrier(0);
      SBAR();
    }                                      // t == KTILES-1: fall through
    cur = (cur == 2) ? 0 : cur + 1;
  }

  // ---- epilogue: bias already folded; just store acc
#pragma unroll
  for (int m = 0; m < 4; ++m)
#pragma unroll
    for (int r = 0; r < 4; ++r) {
      const int rl = wm * 64 + m * 16 + lhi * 4 + r;
      float* orow = out + (size_t)(row0 + rl) * COUT;
#pragma unroll
      for (int n = 0; n < 4; ++n)
        orow[col0 + wn * 64 + n * 16 + llo] = acc[m][n][r];
    }
}

extern "C" void kernel_launch(void* const* d_in, const int* in_sizes, int n_in,
                              void* d_out, int out_size, void* d_ws, size_t ws_size,
                              hipStream_t stream) {
  const float* x    = (const float*)d_in[0];  // [16384][512]
  const float* coef = (const float*)d_in[1];  // [16384][8]
  const float* w    = (const float*)d_in[2];  // [8][512][512]
  const float* bias = (const float*)d_in[3];  // [8][512]
  float* out = (float*)d_out;

  short* xb = (short*)d_ws;                   // 16 MB bf16 x
  short* wb = xb + (size_t)N_TOK * CIN;       // 4 MB bf16 weight

  cvt_all<<<2048, 256, 0, stream>>>(
      (const float4*)x, (const float4*)w, (s16x4*)xb, (s16x4*)wb);

  moe_gemm<<<(N_TOK / BM) * (COUT / BN), 512, 0, stream>>>(xb, wb, coef, bias, out);
}